// Round 1
// baseline (431.644 us; speedup 1.0000x reference)
//
#include <hip/hip_runtime.h>
#include <math.h>

#define B 16
#define N 2000
#define D 25088           // 512*7*7
#define PI2 1.570795f     // 3.14159/2, matches the torch-module constant
#define NCHUNK 10
#define NPER (N / NCHUNK) // 200

__device__ __forceinline__ float wave_sum(float v) {
#pragma unroll
    for (int off = 32; off > 0; off >>= 1) v += __shfl_xor(v, off, 64);
    return v;
}
__device__ __forceinline__ float wave_max(float v) {
#pragma unroll
    for (int off = 32; off > 0; off >>= 1) v = fmaxf(v, __shfl_xor(v, off, 64));
    return v;
}

// ---------------------------------------------------------------------------
// Kernel 1: dots[b][n] = key[b] . mem[n]  (raw key; normalization cancels in
// cosine), and mn2[n] = ||mem[n]||^2. One block per 4 memory rows.
// Register tile: 4 n  x 16 b scalar accumulators -> 64 FMA per (16+4) loads.
// ---------------------------------------------------------------------------
__global__ __launch_bounds__(256, 4) void k_dots(const float* __restrict__ key,
                                                 const float* __restrict__ mem,
                                                 float* __restrict__ dots,
                                                 float* __restrict__ mn2) {
    const int tid = threadIdx.x;
    const int n0  = blockIdx.x * 4;
    const float* mrow = mem + (size_t)n0 * D;

    float acc[4][B];
    float msq[4] = {0.f, 0.f, 0.f, 0.f};
#pragma unroll
    for (int j = 0; j < 4; ++j)
#pragma unroll
        for (int b = 0; b < B; ++b) acc[j][b] = 0.f;

    for (int i = 0; i < D / 256; ++i) {
        const int d = i * 256 + tid;
        float kv[B];
#pragma unroll
        for (int b = 0; b < B; ++b) kv[b] = key[(size_t)b * D + d];
        float mv[4];
#pragma unroll
        for (int j = 0; j < 4; ++j) mv[j] = mrow[(size_t)j * D + d];
#pragma unroll
        for (int j = 0; j < 4; ++j) {
            msq[j] = fmaf(mv[j], mv[j], msq[j]);
#pragma unroll
            for (int b = 0; b < B; ++b) acc[j][b] = fmaf(kv[b], mv[j], acc[j][b]);
        }
    }

    // Block reduction: wave shuffle, then 4 partials via LDS.
    __shared__ float lds[4][68];
    const int wv = tid >> 6, ln = tid & 63;
#pragma unroll
    for (int j = 0; j < 4; ++j) {
#pragma unroll
        for (int b = 0; b < B; ++b) {
            float v = wave_sum(acc[j][b]);
            if (ln == 0) lds[wv][j * B + b] = v;
        }
        float v = wave_sum(msq[j]);
        if (ln == 0) lds[wv][64 + j] = v;
    }
    __syncthreads();
    if (tid < 68) {
        float v = lds[0][tid] + lds[1][tid] + lds[2][tid] + lds[3][tid];
        if (tid < 64) {
            int j = tid >> 4, b = tid & 15;
            dots[(size_t)b * N + n0 + j] = v;
        } else {
            mn2[n0 + (tid - 64)] = v;
        }
    }
}

// ---------------------------------------------------------------------------
// Kernel 2: per-b softmax of tan(cos * PI/2). One block per b.
// Fuses ||key_b||^2 reduction. Small: reads 100 KB key + 2000 dots per block.
// ---------------------------------------------------------------------------
__global__ __launch_bounds__(256, 4) void k_softmax(const float* __restrict__ key,
                                                    const float* __restrict__ dots,
                                                    const float* __restrict__ mn2,
                                                    float* __restrict__ w) {
    const int b = blockIdx.x, tid = threadIdx.x;
    const int wv = tid >> 6, ln = tid & 63;
    __shared__ float t[N];
    __shared__ float redA[4], redB[4], redC[4];

    // ||key_b||^2
    float s = 0.f;
    for (int i = tid; i < D; i += 256) {
        float v = key[(size_t)b * D + i];
        s = fmaf(v, v, s);
    }
    s = wave_sum(s);
    if (ln == 0) redA[wv] = s;
    __syncthreads();
    const float kn = fmaxf(sqrtf(redA[0] + redA[1] + redA[2] + redA[3]), 1e-8f);

    // logits + max
    float mx = -1e30f;
    for (int n = tid; n < N; n += 256) {
        float mn  = fmaxf(sqrtf(mn2[n]), 1e-8f);
        float cs  = dots[(size_t)b * N + n] / (kn * mn);
        float tv  = tanf(cs * PI2);
        t[n] = tv;
        mx = fmaxf(mx, tv);
    }
    mx = wave_max(mx);
    if (ln == 0) redB[wv] = mx;
    __syncthreads();
    mx = fmaxf(fmaxf(redB[0], redB[1]), fmaxf(redB[2], redB[3]));

    // exp + sum
    float sum = 0.f;
    for (int n = tid; n < N; n += 256) {
        float e = expf(t[n] - mx);
        t[n] = e;
        sum += e;
    }
    sum = wave_sum(sum);
    if (ln == 0) redC[wv] = sum;
    __syncthreads();
    sum = redC[0] + redC[1] + redC[2] + redC[3];
    const float inv = 1.f / sum;
    for (int n = tid; n < N; n += 256) w[(size_t)b * N + n] = t[n] * inv;
}

// ---------------------------------------------------------------------------
// Kernel 3: out[b][d] = sum_n w[b][n] * mem[n][d].
// Grid (D/256, NCHUNK); w index is wave-uniform -> scalar loads; memory should
// be L3-resident after k_dots. Partials merged with fp32 HW atomics.
// ---------------------------------------------------------------------------
__global__ __launch_bounds__(256, 4) void k_out(const float* __restrict__ mem,
                                                const float* __restrict__ w,
                                                float* __restrict__ out) {
    const int d  = blockIdx.x * 256 + threadIdx.x;
    const int n0 = blockIdx.y * NPER;
    float acc[B];
#pragma unroll
    for (int b = 0; b < B; ++b) acc[b] = 0.f;
    for (int n = n0; n < n0 + NPER; ++n) {
        const float mv = mem[(size_t)n * D + d];
#pragma unroll
        for (int b = 0; b < B; ++b) acc[b] = fmaf(w[(size_t)b * N + n], mv, acc[b]);
    }
#pragma unroll
    for (int b = 0; b < B; ++b) unsafeAtomicAdd(&out[(size_t)b * D + d], acc[b]);
}

extern "C" void kernel_launch(void* const* d_in, const int* in_sizes, int n_in,
                              void* d_out, int out_size, void* d_ws, size_t ws_size,
                              hipStream_t stream) {
    const float* key = (const float*)d_in[0];   // [16, 512, 7, 7]
    const float* mem = (const float*)d_in[1];   // [2000, 512, 7, 7]
    float* out = (float*)d_out;                 // [16, 512, 7, 7]

    float* ws   = (float*)d_ws;
    float* dots = ws;                 // B*N   = 32000
    float* mn2  = ws + (size_t)B * N; // N     =  2000
    float* w    = mn2 + N;            // B*N   = 32000

    hipMemsetAsync(d_out, 0, (size_t)B * D * sizeof(float), stream);
    k_dots<<<dim3(N / 4), 256, 0, stream>>>(key, mem, dots, mn2);
    k_softmax<<<dim3(B), 256, 0, stream>>>(key, dots, mn2, w);
    k_out<<<dim3(D / 256, NCHUNK), 256, 0, stream>>>(mem, w, out);
}